// Round 4
// baseline (249.576 us; speedup 1.0000x reference)
//
#include <hip/hip_runtime.h>
#include <hip/hip_bf16.h>

#define N_NODES 100000
#define N_EDGES 1600000
#define HID 64

#define NTILES 6250     // N_NODES/16 — one bin per 16-node MFMA tile
#define TCAP 384        // slots per tile; Poisson(256), +8 sigma
#define EPT 16          // edges per thread in bin path (256 thr -> 4096/block)
#define BIN_BLOCKS 391  // ceil(1600000/4096)
#define LIN_BLOCKS 1563 // ceil(6250 tiles / 4 waves per block)
#define GWAVES 8        // gather: 8 waves/block, one tile per wave
#define GBLOCKS 782     // ceil(6250/8)

using bf16 = __hip_bfloat16;
typedef __attribute__((ext_vector_type(8))) short short8;
typedef __attribute__((ext_vector_type(4))) short short4v;
typedef __attribute__((ext_vector_type(4))) float float4v;

__device__ __forceinline__ float bfbits2f(unsigned short u) {
    union { unsigned int i; float f; } v;
    v.i = ((unsigned int)u) << 16;
    return v.f;
}
__device__ __forceinline__ unsigned short f2bfbits(float f) {
    union { float f; unsigned int i; } v;
    v.f = f;
    unsigned int r = v.i + 0x7fffu + ((v.i >> 16) & 1u);  // RNE; finite inputs
    return (unsigned short)(r >> 16);
}

// Init: zero per-tile cursors; build W fragment-order planes so prep2's
// B-frag loads are lane-contiguous: Wf[((nt*2+ks)*64 + l)*8 + j] holds
// W[nt*16+(l&15)][ks*32+(l>>4)*8+j] split into bf16 hi/lo.
__global__ __launch_bounds__(256) void k_init(
    const float* __restrict__ W, int* __restrict__ gcur,
    unsigned short* __restrict__ Wfhi, unsigned short* __restrict__ Wflo)
{
    const int t = blockIdx.x * 256 + threadIdx.x;
    for (int i = t; i < 6272; i += 512) gcur[i] = 0;
    for (int o = t; o < HID * HID; o += 512) {
        const int j = o & 7, l = (o >> 3) & 63, ksnt = o >> 9;
        const int ks = ksnt & 1, nt = ksnt >> 1;
        const int c = l & 15, q = l >> 4;
        const float f = W[(size_t)(nt * 16 + c) * HID + ks * 32 + q * 8 + j];
        const unsigned short h = f2bfbits(f);
        Wfhi[o] = h;
        Wflo[o] = f2bfbits(f - bfbits2f(h));
    }
}

// Fused: blocks [0,LIN_BLOCKS) = MFMA linear (R1-proven: x staged via LDS so
// global reads are coalesced; W-frags from pre-swizzled planes).
// Blocks [LIN_BLOCKS,...) = per-TILE edge binning: tile = dst>>4, direct
// global atomicAdd per edge (256 adds/counter — no LDS phase at all).
__global__ __launch_bounds__(256, 4) void k_prep2(
    const float* __restrict__ x, const unsigned short* __restrict__ Wfhi,
    const unsigned short* __restrict__ Wflo, const float* __restrict__ b,
    bf16* __restrict__ m,
    const int* __restrict__ edges, int* __restrict__ gcur,
    int* __restrict__ binned)
{
    __shared__ float xs[64 * 65];                    // 16.6 KB, pad 65
    const int t = threadIdx.x;

    if (blockIdx.x < LIN_BLOCKS) {
        // Stage 64 node rows coalesced into LDS (padded stride 65).
        const int nb0 = blockIdx.x * 64;
        const float4* xg = reinterpret_cast<const float4*>(x) + (size_t)nb0 * 16;
        #pragma unroll
        for (int k = 0; k < 4; ++k) {
            const int f4 = t + k * 256;                 // float4 idx within block
            float4 v = make_float4(0.f, 0.f, 0.f, 0.f);
            if (nb0 * 16 + f4 < N_NODES * 16) v = xg[f4];
            const int r = f4 >> 4, fc = (f4 & 15) * 4;
            float* dst = &xs[r * 65 + fc];
            dst[0] = v.x; dst[1] = v.y; dst[2] = v.z; dst[3] = v.w;
        }
        __syncthreads();

        const int wv = t >> 6, l = t & 63;
        const int c = l & 15, q = l >> 4;
        const int tile = blockIdx.x * 4 + wv;
        if (tile >= NTILES) return;   // 6250 tiles cover 100k nodes exactly
        const int nb = tile * 16;

        // B-frags: lane-contiguous loads from pre-swizzled planes.
        const short8* wfh = reinterpret_cast<const short8*>(Wfhi);
        const short8* wfl = reinterpret_cast<const short8*>(Wflo);
        short8 Bhi[4][2], Blo[4][2];
        #pragma unroll
        for (int nt = 0; nt < 4; ++nt)
            #pragma unroll
            for (int ks = 0; ks < 2; ++ks) {
                const int fi = (nt * 2 + ks) * 64 + l;
                Bhi[nt][ks] = wfh[fi];
                Blo[nt][ks] = wfl[fi];
            }

        // A-frags from LDS (bank-conflict-free via pad), bf16 RNE convert.
        short8 Ahi[2];
        #pragma unroll
        for (int ks = 0; ks < 2; ++ks) {
            const float* xsrc = &xs[(wv * 16 + c) * 65 + ks * 32 + q * 8];
            #pragma unroll
            for (int j = 0; j < 8; ++j)
                Ahi[ks][j] = (short)f2bfbits(xsrc[j]);
        }

        float4v acc[4];
        #pragma unroll
        for (int nt = 0; nt < 4; ++nt) {
            const float bias = b[nt * 16 + c];
            acc[nt] = (float4v){bias, bias, bias, bias};
            #pragma unroll
            for (int ks = 0; ks < 2; ++ks) {
                acc[nt] = __builtin_amdgcn_mfma_f32_16x16x32_bf16(Ahi[ks], Bhi[nt][ks], acc[nt], 0, 0, 0);
                acc[nt] = __builtin_amdgcn_mfma_f32_16x16x32_bf16(Ahi[ks], Blo[nt][ks], acc[nt], 0, 0, 0);
            }
        }

        // C/D: col c = feature nt*16+c, row q*4+rg = node nb+q*4+rg
        unsigned short* mp = reinterpret_cast<unsigned short*>(m);
        #pragma unroll
        for (int nt = 0; nt < 4; ++nt)
            #pragma unroll
            for (int rg = 0; rg < 4; ++rg) {
                const float v = fmaxf(acc[nt][rg], 0.0f);
                mp[(size_t)(nb + q * 4 + rg) * HID + nt * 16 + c] = f2bfbits(v);
            }
    } else {
        // Per-tile binning: no LDS, no barriers. 16 independent edges/thread.
        const int bb = blockIdx.x - LIN_BLOCKS;
        const int e0 = bb * (256 * EPT);
        #pragma unroll
        for (int k = 0; k < EPT; ++k) {
            const int e = e0 + k * 256 + t;   // coalesced per k
            if (e < N_EDGES) {
                const int dst = edges[e];             // target
                const int src = edges[N_EDGES + e];   // source
                const int tile = dst >> 4;
                const int slot = atomicAdd(&gcur[tile], 1);
                if (slot < TCAP)
                    binned[(size_t)tile * TCAP + slot] = ((dst & 15) << 17) | src;
            }
        }
    }
}

// hardware transpose read: per-lane addr = base + l*8; group q (l>>4) reads the
// 128B window at q*128: [4 slots][16 feats] bf16 row-major; lane gets feat l&15
// across the 4 slot-rows (learn_hip m156/m162 semantics).
#define TRREAD(dst, OFF) \
    asm volatile("ds_read_b64_tr_b16 %0, %1 offset:" #OFF \
                 : "=v"(dst) : "v"(traddr) : "memory")

// MFMA gather, phase-free: 8 waves/block, each wave = one 16-node tile, list
// streamed directly from global (int2 addresses / int4 one-hot tags — all in
// one L1-hot 128B line per chunk). No list build, no LDS atomics, no barrier.
// Per 32-slot chunk: 4 gathered dwordx4 m-rows (prefetched one chunk ahead),
// 4 conflict-free ds_write_b128 (offset mod 128 = (l&7)*16), 8 tr-reads, 4
// MFMA vs one-hot B. Window row r holds slot 2r (pass A) / 2r+1 (pass B) ->
// k-order [0,2,4,6,1,3,5,7], compensated in the one-hot build. Slots >= K are
// masked in the one-hot and address-clamped to slot 0 (harmless duplicate).
// 16 KB LDS + <=64 VGPR -> 4 blocks/CU = 32 waves/CU.
__global__ __launch_bounds__(512, 8) void k_gather_mfma(
    const float* __restrict__ x, const bf16* __restrict__ m,
    const int* __restrict__ gcur, const int* __restrict__ binned,
    const float* __restrict__ nw, const float* __restrict__ nbias,
    float* __restrict__ out)
{
    __shared__ uint4 stg4[GWAVES * 128];                // 16 KB: 2KB per wave
    const int t = threadIdx.x;
    const int wv = t >> 6, l = t & 63;
    const int tg = blockIdx.x * GWAVES + wv;            // global tile id
    if (tg >= NTILES) return;                           // no barriers: safe

    const int q = l >> 4;            // MFMA k-group / tr-read window
    const int node16 = l & 15;       // node column this lane owns in D
    const int h  = l & 1;            // 16B half within a window row
    const int r2 = (l >> 1) & 3;     // window row this lane stages
    const int ft = (l >> 3) & 3;     // feat-16 group this lane stages
    const int qb = (l >> 5) & 1;     // window base (stores: qb and qb+2)
    const int fq = ft * 2 + h;       // 16B segment of the m-row to gather
    const int sA0 = qb * 8 + r2 * 2; // chunk-local slot (pass A); +1 pass B
    // conflict-free write offset: mod 128 = (r2*32 + h*16) = (l&7)*16
    const int wbyte = ft * 512 + qb * 128 + r2 * 32 + h * 16;
    char* stg_wave = (char*)(&stg4[0]) + (wv << 11);
    const unsigned traddr = (unsigned)(size_t)stg_wave + (unsigned)(l << 3);
    const uint4* mv = reinterpret_cast<const uint4*>(m);

    int K = gcur[tg];
    if (K > TCAP) K = TCAP;
    const int* list = binned + (size_t)tg * TCAP;
    const int nch = (K + 31) >> 5;

    float4v acc0 = {0.f, 0.f, 0.f, 0.f};
    float4v acc1 = acc0, acc2 = acc0, acc3 = acc0;

    if (nch > 0) {
        // prologue: chunk 0 addresses + rows (clamp OOB slots to 0; masked)
        const int ka = sA0, kb2 = sA0 + 16;
        int2 pa = *reinterpret_cast<const int2*>(list + ((ka  < K) ? ka  : 0));
        int2 pb = *reinterpret_cast<const int2*>(list + ((kb2 < K) ? kb2 : 0));
        uint4 dA0 = mv[(size_t)(pa.x & 0x1FFFF) * 8 + fq];
        uint4 dB0 = mv[(size_t)(pa.y & 0x1FFFF) * 8 + fq];
        uint4 dA1 = mv[(size_t)(pb.x & 0x1FFFF) * 8 + fq];
        uint4 dB1 = mv[(size_t)(pb.y & 0x1FFFF) * 8 + fq];

        for (int ch = 0; ch < nch; ++ch) {
            const int k0 = ch << 5;
            // --- prefetch next chunk (wraps to 0 on last iter; harmless) ---
            const int kn = (ch + 1 < nch) ? (k0 + 32) : 0;
            const int na = kn + sA0, nb2 = kn + sA0 + 16;
            const int2 npa = *reinterpret_cast<const int2*>(list + ((na  < K) ? na  : 0));
            const int2 npb = *reinterpret_cast<const int2*>(list + ((nb2 < K) ? nb2 : 0));
            const uint4 nA0 = mv[(size_t)(npa.x & 0x1FFFF) * 8 + fq];
            const uint4 nB0 = mv[(size_t)(npa.y & 0x1FFFF) * 8 + fq];
            const uint4 nA1 = mv[(size_t)(npb.x & 0x1FFFF) * 8 + fq];
            const uint4 nB1 = mv[(size_t)(npb.y & 0x1FFFF) * 8 + fq];

            // --- one-hot tags: 2 x int4, k-order compensated [0,2,4,6,1,3,5,7];
            //     slots >= K masked (global tail is poison) ---
            const int tb = k0 + q * 8;
            const int4 t0 = *reinterpret_cast<const int4*>(list + tb);
            const int4 t1 = *reinterpret_cast<const int4*>(list + tb + 4);
            short8 bh;
            bh[0] = (short)(((tb + 0 < K) && ((t0.x >> 17) == node16)) ? 0x3F80 : 0);
            bh[4] = (short)(((tb + 1 < K) && ((t0.y >> 17) == node16)) ? 0x3F80 : 0);
            bh[1] = (short)(((tb + 2 < K) && ((t0.z >> 17) == node16)) ? 0x3F80 : 0);
            bh[5] = (short)(((tb + 3 < K) && ((t0.w >> 17) == node16)) ? 0x3F80 : 0);
            bh[2] = (short)(((tb + 4 < K) && ((t1.x >> 17) == node16)) ? 0x3F80 : 0);
            bh[6] = (short)(((tb + 5 < K) && ((t1.y >> 17) == node16)) ? 0x3F80 : 0);
            bh[3] = (short)(((tb + 6 < K) && ((t1.z >> 17) == node16)) ? 0x3F80 : 0);
            bh[7] = (short)(((tb + 7 < K) && ((t1.w >> 17) == node16)) ? 0x3F80 : 0);

            // --- pass A (slots 2r): stage windows qb, qb+2; transpose-read ---
            *reinterpret_cast<uint4*>(stg_wave + wbyte) = dA0;
            *reinterpret_cast<uint4*>(stg_wave + wbyte + 256) = dA1;
            short4v tA0, tA1, tA2, tA3;
            TRREAD(tA0, 0); TRREAD(tA1, 512); TRREAD(tA2, 1024); TRREAD(tA3, 1536);

            // --- pass B (slots 2r+1): same addresses (DS pipe is in-order) ---
            *reinterpret_cast<uint4*>(stg_wave + wbyte) = dB0;
            *reinterpret_cast<uint4*>(stg_wave + wbyte + 256) = dB1;
            short4v tB0, tB1, tB2, tB3;
            TRREAD(tB0, 0); TRREAD(tB1, 512); TRREAD(tB2, 1024); TRREAD(tB3, 1536);

            asm volatile("s_waitcnt lgkmcnt(0)" ::: "memory");
            __builtin_amdgcn_sched_barrier(0);
            const short8 a0 = __builtin_shufflevector(tA0, tB0, 0, 1, 2, 3, 4, 5, 6, 7);
            const short8 a1 = __builtin_shufflevector(tA1, tB1, 0, 1, 2, 3, 4, 5, 6, 7);
            const short8 a2 = __builtin_shufflevector(tA2, tB2, 0, 1, 2, 3, 4, 5, 6, 7);
            const short8 a3 = __builtin_shufflevector(tA3, tB3, 0, 1, 2, 3, 4, 5, 6, 7);
            acc0 = __builtin_amdgcn_mfma_f32_16x16x32_bf16(a0, bh, acc0, 0, 0, 0);
            acc1 = __builtin_amdgcn_mfma_f32_16x16x32_bf16(a1, bh, acc1, 0, 0, 0);
            acc2 = __builtin_amdgcn_mfma_f32_16x16x32_bf16(a2, bh, acc2, 0, 0, 0);
            acc3 = __builtin_amdgcn_mfma_f32_16x16x32_bf16(a3, bh, acc3, 0, 0, 0);

            // --- rotate prefetch into current ---
            pa = npa; pb = npb;
            dA0 = nA0; dB0 = nB0; dA1 = nA1; dB1 = nB1;
        }
    }

    // --- epilogue: residual + RMSNorm. Lane holds feats ft*16+q*4+{0..3} of
    // node tg*16 + node16 (exact: 6250*16 == 100000). ss partners l^16,l^32. ---
    const int n = tg * 16 + node16;
    {
        const float4* xr = reinterpret_cast<const float4*>(x) + (size_t)n * 16 + q;
        const float4 x0 = xr[0], x1 = xr[4], x2 = xr[8], x3 = xr[12];
        const float h00 = x0.x + acc0[0], h01 = x0.y + acc0[1], h02 = x0.z + acc0[2], h03 = x0.w + acc0[3];
        const float h10 = x1.x + acc1[0], h11 = x1.y + acc1[1], h12 = x1.z + acc1[2], h13 = x1.w + acc1[3];
        const float h20 = x2.x + acc2[0], h21 = x2.y + acc2[1], h22 = x2.z + acc2[2], h23 = x2.w + acc2[3];
        const float h30 = x3.x + acc3[0], h31 = x3.y + acc3[1], h32 = x3.z + acc3[2], h33 = x3.w + acc3[3];
        float ss = h00 * h00 + h01 * h01 + h02 * h02 + h03 * h03
                 + h10 * h10 + h11 * h11 + h12 * h12 + h13 * h13
                 + h20 * h20 + h21 * h21 + h22 * h22 + h23 * h23
                 + h30 * h30 + h31 * h31 + h32 * h32 + h33 * h33;
        ss += __shfl_xor(ss, 16, 64);
        ss += __shfl_xor(ss, 32, 64);
        const float inv = rsqrtf(ss * (1.0f / HID) + 1e-5f);
        const float4* nwp = reinterpret_cast<const float4*>(nw);
        const float4* nbp = reinterpret_cast<const float4*>(nbias);
        float4* op = reinterpret_cast<float4*>(out) + (size_t)n * 16 + q;
        {
            const float4 w = nwp[q], bb = nbp[q];
            float4 o;
            o.x = w.x * h00 * inv + bb.x; o.y = w.y * h01 * inv + bb.y;
            o.z = w.z * h02 * inv + bb.z; o.w = w.w * h03 * inv + bb.w;
            op[0] = o;
        }
        {
            const float4 w = nwp[4 + q], bb = nbp[4 + q];
            float4 o;
            o.x = w.x * h10 * inv + bb.x; o.y = w.y * h11 * inv + bb.y;
            o.z = w.z * h12 * inv + bb.z; o.w = w.w * h13 * inv + bb.w;
            op[4] = o;
        }
        {
            const float4 w = nwp[8 + q], bb = nbp[8 + q];
            float4 o;
            o.x = w.x * h20 * inv + bb.x; o.y = w.y * h21 * inv + bb.y;
            o.z = w.z * h22 * inv + bb.z; o.w = w.w * h23 * inv + bb.w;
            op[8] = o;
        }
        {
            const float4 w = nwp[12 + q], bb = nbp[12 + q];
            float4 o;
            o.x = w.x * h30 * inv + bb.x; o.y = w.y * h31 * inv + bb.y;
            o.z = w.z * h32 * inv + bb.z; o.w = w.w * h33 * inv + bb.w;
            op[12] = o;
        }
    }
}

extern "C" void kernel_launch(void* const* d_in, const int* in_sizes, int n_in,
                              void* d_out, int out_size, void* d_ws, size_t ws_size,
                              hipStream_t stream) {
    const float* x     = (const float*)d_in[0];
    const int*   edges = (const int*)d_in[1];
    const float* W     = (const float*)d_in[2];
    const float* b     = (const float*)d_in[3];
    const float* nw    = (const float*)d_in[4];
    const float* nb    = (const float*)d_in[5];
    float* out = (float*)d_out;

    // Workspace: gcur 25KB @0 | Wfhi 8KB @32K | Wflo 8KB @40K |
    //            binned 9.6MB @64K ((NTILES+1)*TCAP ints, +1 tile pad) | m after
    int* gcur = (int*)d_ws;
    unsigned short* Wfhi = (unsigned short*)((char*)d_ws + (1 << 15));
    unsigned short* Wflo = Wfhi + HID * HID;
    int*  binned = (int*)((char*)d_ws + (1 << 16));
    bf16* m      = (bf16*)((char*)d_ws + (1 << 16) +
                           (size_t)(NTILES + 1) * TCAP * sizeof(int));

    k_init<<<2, 256, 0, stream>>>(W, gcur, Wfhi, Wflo);
    k_prep2<<<LIN_BLOCKS + BIN_BLOCKS, 256, 0, stream>>>(x, Wfhi, Wflo, b, m, edges, gcur, binned);
    k_gather_mfma<<<GBLOCKS, 512, 0, stream>>>(x, m, gcur, binned, nw, nb, out);
}

// Round 5
// 149.261 us; speedup vs baseline: 1.6721x; 1.6721x over previous
//
#include <hip/hip_runtime.h>
#include <hip/hip_bf16.h>

#define N_NODES 100000
#define N_EDGES 1600000
#define HID 64

#define NG 196          // nodes per group; 511 groups = exactly 2 blocks/CU
#define GROUPS 511      // ceil(100000/196)
#define GSTRIDE 512     // padded stride for counters/regions
#define NREP 2          // replica regions per group
#define RCAP 2048       // pairs per (replica,group); mean ~1564, +12 sigma
#define EPT 16          // edges per thread in bin path (256 thr -> 4096/block)
#define BIN_BLOCKS 391  // ceil(1600000/4096)
#define LIN_BLOCKS 1563 // ceil(6250 tiles / 4 waves per block)

// gather kernel geometry
#define TILES 13        // ceil(196/16); tile 12 has only 4 nodes (~64 edges)
#define TCAP 384        // slots per tile list; Poisson(~251), +8 sigma
#define GTHREADS 768
#define GWAVES 12
#define PADTAG (16 << 17)   // sentinel: node id 16 (no lane matches), row 0

using bf16 = __hip_bfloat16;
typedef __attribute__((ext_vector_type(8))) short short8;
typedef __attribute__((ext_vector_type(4))) short short4v;
typedef __attribute__((ext_vector_type(4))) float float4v;

__device__ __forceinline__ float bfbits2f(unsigned short u) {
    union { unsigned int i; float f; } v;
    v.i = ((unsigned int)u) << 16;
    return v.f;
}
__device__ __forceinline__ unsigned short f2bfbits(float f) {
    union { float f; unsigned int i; } v;
    v.f = f;
    unsigned int r = v.i + 0x7fffu + ((v.i >> 16) & 1u);  // RNE; finite inputs
    return (unsigned short)(r >> 16);
}

// Init: zero ALL group cursors; build W fragment-order planes so prep2's
// B-frag loads are lane-contiguous: Wf[((nt*2+ks)*64 + l)*8 + j] holds
// W[nt*16+(l&15)][ks*32+(l>>4)*8+j] split into bf16 hi/lo.
__global__ __launch_bounds__(256) void k_init(
    const float* __restrict__ W, int* __restrict__ gcur,
    unsigned short* __restrict__ Wfhi, unsigned short* __restrict__ Wflo)
{
    const int t = blockIdx.x * 256 + threadIdx.x;
    for (int i = t; i < NREP * GSTRIDE; i += 512) gcur[i] = 0;
    for (int o = t; o < HID * HID; o += 512) {
        const int j = o & 7, l = (o >> 3) & 63, ksnt = o >> 9;
        const int ks = ksnt & 1, nt = ksnt >> 1;
        const int c = l & 15, q = l >> 4;
        const float f = W[(size_t)(nt * 16 + c) * HID + ks * 32 + q * 8 + j];
        const unsigned short h = f2bfbits(f);
        Wfhi[o] = h;
        Wflo[o] = f2bfbits(f - bfbits2f(h));
    }
}

// Fused: blocks [0,LIN_BLOCKS) = MFMA linear (R1-proven: x staged via LDS so
// global reads are coalesced; W-frags from pre-swizzled planes). Blocks
// [LIN_BLOCKS,...) = two-phase LDS group binning (R1-proven: contiguous
// per-(block,group) writes -> no write amplification, amortized atomics).
__global__ __launch_bounds__(256, 4) void k_prep2(
    const float* __restrict__ x, const unsigned short* __restrict__ Wfhi,
    const unsigned short* __restrict__ Wflo, const float* __restrict__ b,
    bf16* __restrict__ m,
    const int* __restrict__ edges, int* __restrict__ gcur,
    int* __restrict__ binned)
{
    __shared__ union SM {
        struct { float xs[64 * 65]; } lin;                    // 16.6 KB, pad 65
        struct { int cnt[GSTRIDE]; int base[GSTRIDE]; } bin;  // 4 KB
    } sm;
    const int t = threadIdx.x;

    if (blockIdx.x < LIN_BLOCKS) {
        // Stage 64 node rows coalesced into LDS (padded stride 65).
        const int nb0 = blockIdx.x * 64;
        const float4* xg = reinterpret_cast<const float4*>(x) + (size_t)nb0 * 16;
        #pragma unroll
        for (int k = 0; k < 4; ++k) {
            const int f4 = t + k * 256;                 // float4 idx within block
            float4 v = make_float4(0.f, 0.f, 0.f, 0.f);
            if (nb0 * 16 + f4 < N_NODES * 16) v = xg[f4];
            const int r = f4 >> 4, fc = (f4 & 15) * 4;
            float* dst = &sm.lin.xs[r * 65 + fc];
            dst[0] = v.x; dst[1] = v.y; dst[2] = v.z; dst[3] = v.w;
        }
        __syncthreads();

        const int wv = t >> 6, l = t & 63;
        const int c = l & 15, q = l >> 4;
        const int tile = blockIdx.x * 4 + wv;
        if (tile >= N_NODES / 16) return;   // 6250 tiles cover 100k nodes exactly
        const int nb = tile * 16;

        // B-frags: lane-contiguous loads from pre-swizzled planes.
        const short8* wfh = reinterpret_cast<const short8*>(Wfhi);
        const short8* wfl = reinterpret_cast<const short8*>(Wflo);
        short8 Bhi[4][2], Blo[4][2];
        #pragma unroll
        for (int nt = 0; nt < 4; ++nt)
            #pragma unroll
            for (int ks = 0; ks < 2; ++ks) {
                const int fi = (nt * 2 + ks) * 64 + l;
                Bhi[nt][ks] = wfh[fi];
                Blo[nt][ks] = wfl[fi];
            }

        // A-frags from LDS (bank-conflict-free via pad), bf16 RNE convert.
        short8 Ahi[2];
        #pragma unroll
        for (int ks = 0; ks < 2; ++ks) {
            const float* xsrc = &sm.lin.xs[(wv * 16 + c) * 65 + ks * 32 + q * 8];
            #pragma unroll
            for (int j = 0; j < 8; ++j)
                Ahi[ks][j] = (short)f2bfbits(xsrc[j]);
        }

        float4v acc[4];
        #pragma unroll
        for (int nt = 0; nt < 4; ++nt) {
            const float bias = b[nt * 16 + c];
            acc[nt] = (float4v){bias, bias, bias, bias};
            #pragma unroll
            for (int ks = 0; ks < 2; ++ks) {
                acc[nt] = __builtin_amdgcn_mfma_f32_16x16x32_bf16(Ahi[ks], Bhi[nt][ks], acc[nt], 0, 0, 0);
                acc[nt] = __builtin_amdgcn_mfma_f32_16x16x32_bf16(Ahi[ks], Blo[nt][ks], acc[nt], 0, 0, 0);
            }
        }

        // C/D: col c = feature nt*16+c, row q*4+rg = node nb+q*4+rg
        unsigned short* mp = reinterpret_cast<unsigned short*>(m);
        #pragma unroll
        for (int nt = 0; nt < 4; ++nt)
            #pragma unroll
            for (int rg = 0; rg < 4; ++rg) {
                const float v = fmaxf(acc[nt][rg], 0.0f);
                mp[(size_t)(nb + q * 4 + rg) * HID + nt * 16 + c] = f2bfbits(v);
            }
    } else {
        int* cnt  = sm.bin.cnt;
        int* base = sm.bin.base;
        const int bb = blockIdx.x - LIN_BLOCKS;
        for (int i = t; i < GSTRIDE; i += 256) cnt[i] = 0;
        __syncthreads();

        const int e0 = bb * (256 * EPT);
        int gk[EPT], pk[EPT], sl[EPT];
        #pragma unroll
        for (int k = 0; k < EPT; ++k) {
            const int e = e0 + k * 256 + t;   // coalesced per k
            if (e < N_EDGES) {
                const int dst = edges[e];             // target
                const int src = edges[N_EDGES + e];   // source
                const int g = (int)((unsigned)dst / NG);   // magic-mul div
                gk[k] = g;
                pk[k] = ((dst - g * NG) << 17) | src;  // dl(8b) | src(17b)
                sl[k] = atomicAdd(&cnt[g], 1);
            } else gk[k] = -1;
        }
        __syncthreads();
        const int r = bb & (NREP - 1);
        for (int i = t; i < GROUPS; i += 256) {
            const int cc = cnt[i];
            base[i] = cc ? atomicAdd(&gcur[r * GSTRIDE + i], cc) : 0;
        }
        __syncthreads();
        #pragma unroll
        for (int k = 0; k < EPT; ++k) {
            if (gk[k] >= 0) {
                const int pos = base[gk[k]] + sl[k];
                if ((unsigned)pos < RCAP)   // unsigned: rejects corruption too
                    binned[(size_t)(r * GSTRIDE + gk[k]) * RCAP + pos] = pk[k];
            }
        }
    }
}

// hardware transpose read: per-lane addr = base + l*8; group q (l>>4) reads the
// 128B window at q*128: [4 slots][16 feats] bf16 row-major; lane gets feat l&15
// across the 4 slot-rows (learn_hip m156/m162 semantics).
#define TRREAD(dst, OFF) \
    asm volatile("ds_read_b64_tr_b16 %0, %1 offset:" #OFF \
                 : "=v"(dst) : "v"(traddr) : "memory")

// MFMA gather: R1 structure (one block per 196-node group, LDS phase-1 list
// build, 13 tiles over 12 waves) + R3-verified main loop (conflict-free
// staging writes: offset mod 128 = (l&7)*16; int2/int4 vector list reads;
// PADTAG tail padding so no per-slot guards; register prefetch rotation).
// Window row r holds slot 2r (pass A) / 2r+1 (pass B) -> k-order
// [0,2,4,6,1,3,5,7], compensated in the one-hot build.
__global__ __launch_bounds__(GTHREADS, 6) void k_gather_mfma(
    const float* __restrict__ x, const bf16* __restrict__ m,
    const int* __restrict__ gcur, const int* __restrict__ binned,
    const float* __restrict__ nw, const float* __restrict__ nbias,
    float* __restrict__ out)
{
    __shared__ int tcnt[TILES];
    __shared__ int tlist[TILES * TCAP];                 // 19968 B
    __shared__ uint4 stg4[GWAVES * 128];                // 24576 B: 2KB per wave

    const int t = threadIdx.x;
    const int g = blockIdx.x;
    if (t < TILES) tcnt[t] = 0;
    __syncthreads();

    // Phase 1: per-tile combined lists. pr = dl(8b)<<17 | src(17b);
    // tile = dl>>4 = pr>>21; tag keeps (dl&15)<<17 | src = pr & 0x1FFFFF.
    #pragma unroll
    for (int rr = 0; rr < NREP; ++rr) {
        int c = gcur[rr * GSTRIDE + g];
        if (c > RCAP) c = RCAP;
        const int* reg = binned + (size_t)(rr * GSTRIDE + g) * RCAP;
        for (int i = t; i < c; i += GTHREADS) {
            const int pr = reg[i];
            const int tile = pr >> 21;
            const int slot = atomicAdd(&tcnt[tile], 1);
            if (slot < TCAP) tlist[tile * TCAP + slot] = pr & 0x1FFFFF;
        }
    }
    __syncthreads();

    const int wv = t >> 6, l = t & 63;
    const int q = l >> 4;            // MFMA k-group / tr-read window
    const int node16 = l & 15;       // node column this lane owns in D
    const int h  = l & 1;            // 16B half within a window row
    const int r2 = (l >> 1) & 3;     // window row this lane stages
    const int ft = (l >> 3) & 3;     // feat-16 group this lane stages
    const int qb = (l >> 5) & 1;     // window base (stores: qb and qb+2)
    const int fq = ft * 2 + h;       // 16B segment of the m-row to gather
    const int sA0 = qb * 8 + r2 * 2; // chunk-local slot (pass A); +1 pass B
    // conflict-free write offset: mod 128 = (r2*32 + h*16) = (l&7)*16
    const int wbyte = ft * 512 + qb * 128 + r2 * 32 + h * 16;
    char* stg_wave = (char*)(&stg4[0]) + (wv << 11);
    const unsigned traddr = (unsigned)(size_t)stg_wave + (unsigned)(l << 3);
    const uint4* mv = reinterpret_cast<const uint4*>(m);

    for (int tile = wv; tile < TILES; tile += GWAVES) {
        int K = tcnt[tile];
        if (K > TCAP) K = TCAP;
        const int lbase = tile * TCAP;
        const int nch = (K + 31) >> 5;

        // pad this tile's list tail so unguarded vector reads are harmless;
        // only the owning wave reads these slots.
        for (int i = K + l; i < nch * 32; i += 64) tlist[lbase + i] = PADTAG;
        asm volatile("s_waitcnt lgkmcnt(0)" ::: "memory");

        float4v acc0 = {0.f, 0.f, 0.f, 0.f};
        float4v acc1 = acc0, acc2 = acc0, acc3 = acc0;

        if (nch > 0) {
            // prologue: chunk 0 addresses + rows
            int2 pa = *reinterpret_cast<const int2*>(&tlist[lbase + sA0]);
            int2 pb = *reinterpret_cast<const int2*>(&tlist[lbase + sA0 + 16]);
            uint4 dA0 = mv[(size_t)(pa.x & 0x1FFFF) * 8 + fq];
            uint4 dB0 = mv[(size_t)(pa.y & 0x1FFFF) * 8 + fq];
            uint4 dA1 = mv[(size_t)(pb.x & 0x1FFFF) * 8 + fq];
            uint4 dB1 = mv[(size_t)(pb.y & 0x1FFFF) * 8 + fq];

            for (int ch = 0; ch < nch; ++ch) {
                const int k0 = ch << 5;
                // --- prefetch next chunk (wraps to 0 on last iter; harmless) ---
                const int kn = (ch + 1 < nch) ? (k0 + 32) : 0;
                const int2 npa = *reinterpret_cast<const int2*>(&tlist[lbase + kn + sA0]);
                const int2 npb = *reinterpret_cast<const int2*>(&tlist[lbase + kn + sA0 + 16]);
                const uint4 nA0 = mv[(size_t)(npa.x & 0x1FFFF) * 8 + fq];
                const uint4 nB0 = mv[(size_t)(npa.y & 0x1FFFF) * 8 + fq];
                const uint4 nA1 = mv[(size_t)(npb.x & 0x1FFFF) * 8 + fq];
                const uint4 nB1 = mv[(size_t)(npb.y & 0x1FFFF) * 8 + fq];

                // --- one-hot tags: 2 x int4, k-order compensated [0,2,4,6,1,3,5,7] ---
                const int tb = k0 + q * 8;
                const int4 t0 = *reinterpret_cast<const int4*>(&tlist[lbase + tb]);
                const int4 t1 = *reinterpret_cast<const int4*>(&tlist[lbase + tb + 4]);
                short8 bh;
                bh[0] = (short)(((t0.x >> 17) == node16) ? 0x3F80 : 0);
                bh[4] = (short)(((t0.y >> 17) == node16) ? 0x3F80 : 0);
                bh[1] = (short)(((t0.z >> 17) == node16) ? 0x3F80 : 0);
                bh[5] = (short)(((t0.w >> 17) == node16) ? 0x3F80 : 0);
                bh[2] = (short)(((t1.x >> 17) == node16) ? 0x3F80 : 0);
                bh[6] = (short)(((t1.y >> 17) == node16) ? 0x3F80 : 0);
                bh[3] = (short)(((t1.z >> 17) == node16) ? 0x3F80 : 0);
                bh[7] = (short)(((t1.w >> 17) == node16) ? 0x3F80 : 0);

                // --- pass A (slots 2r): stage windows qb, qb+2; transpose-read ---
                *reinterpret_cast<uint4*>(stg_wave + wbyte) = dA0;
                *reinterpret_cast<uint4*>(stg_wave + wbyte + 256) = dA1;
                short4v tA0, tA1, tA2, tA3;
                TRREAD(tA0, 0); TRREAD(tA1, 512); TRREAD(tA2, 1024); TRREAD(tA3, 1536);

                // --- pass B (slots 2r+1): same addresses (DS pipe is in-order) ---
                *reinterpret_cast<uint4*>(stg_wave + wbyte) = dB0;
                *reinterpret_cast<uint4*>(stg_wave + wbyte + 256) = dB1;
                short4v tB0, tB1, tB2, tB3;
                TRREAD(tB0, 0); TRREAD(tB1, 512); TRREAD(tB2, 1024); TRREAD(tB3, 1536);

                asm volatile("s_waitcnt lgkmcnt(0)" ::: "memory");
                __builtin_amdgcn_sched_barrier(0);
                const short8 a0 = __builtin_shufflevector(tA0, tB0, 0, 1, 2, 3, 4, 5, 6, 7);
                const short8 a1 = __builtin_shufflevector(tA1, tB1, 0, 1, 2, 3, 4, 5, 6, 7);
                const short8 a2 = __builtin_shufflevector(tA2, tB2, 0, 1, 2, 3, 4, 5, 6, 7);
                const short8 a3 = __builtin_shufflevector(tA3, tB3, 0, 1, 2, 3, 4, 5, 6, 7);
                acc0 = __builtin_amdgcn_mfma_f32_16x16x32_bf16(a0, bh, acc0, 0, 0, 0);
                acc1 = __builtin_amdgcn_mfma_f32_16x16x32_bf16(a1, bh, acc1, 0, 0, 0);
                acc2 = __builtin_amdgcn_mfma_f32_16x16x32_bf16(a2, bh, acc2, 0, 0, 0);
                acc3 = __builtin_amdgcn_mfma_f32_16x16x32_bf16(a3, bh, acc3, 0, 0, 0);

                // --- rotate prefetch into current ---
                pa = npa; pb = npb;
                dA0 = nA0; dB0 = nB0; dA1 = nA1; dB1 = nB1;
            }
        }

        // --- epilogue: residual + RMSNorm. Lane holds feats ft*16+q*4+{0..3}
        // of node g*NG + tile*16 + node16. ss partners (l^16,l^32) share node. ---
        const int dl = (tile << 4) + node16;
        const int n = g * NG + dl;
        if (dl < NG && n < N_NODES) {
            const float4* xr = reinterpret_cast<const float4*>(x) + (size_t)n * 16 + q;
            const float4 x0 = xr[0], x1 = xr[4], x2 = xr[8], x3 = xr[12];
            const float h00 = x0.x + acc0[0], h01 = x0.y + acc0[1], h02 = x0.z + acc0[2], h03 = x0.w + acc0[3];
            const float h10 = x1.x + acc1[0], h11 = x1.y + acc1[1], h12 = x1.z + acc1[2], h13 = x1.w + acc1[3];
            const float h20 = x2.x + acc2[0], h21 = x2.y + acc2[1], h22 = x2.z + acc2[2], h23 = x2.w + acc2[3];
            const float h30 = x3.x + acc3[0], h31 = x3.y + acc3[1], h32 = x3.z + acc3[2], h33 = x3.w + acc3[3];
            float ss = h00 * h00 + h01 * h01 + h02 * h02 + h03 * h03
                     + h10 * h10 + h11 * h11 + h12 * h12 + h13 * h13
                     + h20 * h20 + h21 * h21 + h22 * h22 + h23 * h23
                     + h30 * h30 + h31 * h31 + h32 * h32 + h33 * h33;
            ss += __shfl_xor(ss, 16, 64);
            ss += __shfl_xor(ss, 32, 64);
            const float inv = rsqrtf(ss * (1.0f / HID) + 1e-5f);
            const float4* nwp = reinterpret_cast<const float4*>(nw);
            const float4* nbp = reinterpret_cast<const float4*>(nbias);
            float4* op = reinterpret_cast<float4*>(out) + (size_t)n * 16 + q;
            {
                const float4 w = nwp[q], bb = nbp[q];
                float4 o;
                o.x = w.x * h00 * inv + bb.x; o.y = w.y * h01 * inv + bb.y;
                o.z = w.z * h02 * inv + bb.z; o.w = w.w * h03 * inv + bb.w;
                op[0] = o;
            }
            {
                const float4 w = nwp[4 + q], bb = nbp[4 + q];
                float4 o;
                o.x = w.x * h10 * inv + bb.x; o.y = w.y * h11 * inv + bb.y;
                o.z = w.z * h12 * inv + bb.z; o.w = w.w * h13 * inv + bb.w;
                op[4] = o;
            }
            {
                const float4 w = nwp[8 + q], bb = nbp[8 + q];
                float4 o;
                o.x = w.x * h20 * inv + bb.x; o.y = w.y * h21 * inv + bb.y;
                o.z = w.z * h22 * inv + bb.z; o.w = w.w * h23 * inv + bb.w;
                op[8] = o;
            }
            {
                const float4 w = nwp[12 + q], bb = nbp[12 + q];
                float4 o;
                o.x = w.x * h30 * inv + bb.x; o.y = w.y * h31 * inv + bb.y;
                o.z = w.z * h32 * inv + bb.z; o.w = w.w * h32 * 0.0f + w.w * h33 * inv + bb.w;
                o.w = w.w * h33 * inv + bb.w;
                op[12] = o;
            }
        }
    }
}

extern "C" void kernel_launch(void* const* d_in, const int* in_sizes, int n_in,
                              void* d_out, int out_size, void* d_ws, size_t ws_size,
                              hipStream_t stream) {
    const float* x     = (const float*)d_in[0];
    const int*   edges = (const int*)d_in[1];
    const float* W     = (const float*)d_in[2];
    const float* b     = (const float*)d_in[3];
    const float* nw    = (const float*)d_in[4];
    const float* nb    = (const float*)d_in[5];
    float* out = (float*)d_out;

    // Workspace: gcur 4KB | Wfhi 8KB @16K | Wflo 8KB @24K | binned 8.4MB @64K | m
    int* gcur = (int*)d_ws;
    unsigned short* Wfhi = (unsigned short*)((char*)d_ws + (1 << 14));
    unsigned short* Wflo = Wfhi + HID * HID;
    int*  binned = (int*)((char*)d_ws + (1 << 16));
    bf16* m      = (bf16*)((char*)d_ws + (1 << 16) +
                           (size_t)NREP * GSTRIDE * RCAP * sizeof(int));

    k_init<<<2, 256, 0, stream>>>(W, gcur, Wfhi, Wflo);
    k_prep2<<<LIN_BLOCKS + BIN_BLOCKS, 256, 0, stream>>>(x, Wfhi, Wflo, b, m, edges, gcur, binned);
    k_gather_mfma<<<GROUPS, GTHREADS, 0, stream>>>(x, m, gcur, binned, nw, nb, out);
}

// Round 6
// 147.591 us; speedup vs baseline: 1.6910x; 1.0113x over previous
//
#include <hip/hip_runtime.h>
#include <hip/hip_bf16.h>

#define N_NODES 100000
#define N_EDGES 1600000
#define HID 64

#define NG 196          // nodes per group; 511 groups = exactly 2 blocks/CU
#define GROUPS 511      // ceil(100000/196)
#define GSTRIDE 512     // padded stride for counters/regions
#define NREP 2          // replica regions per group
#define RCAP 2048       // pairs per (replica,group); mean ~1564, +12 sigma
#define EPT 16          // edges per thread in bin path (256 thr -> 4096/block)
#define BIN_BLOCKS 391  // ceil(1600000/4096)
#define LIN_BLOCKS 1563 // ceil(6250 tiles / 4 waves per block)

// gather kernel geometry
#define TILES 13        // ceil(196/16); tile 12 has only 4 nodes (~64 edges)
#define TCAP 384        // slots per tile list; Poisson(~251), +8 sigma
#define GTHREADS 768
#define GWAVES 12
#define NOCT 8          // src octants (src>>14 in [0,6]; slot 7 ~empty)
#define PADTAG (16 << 17)   // sentinel: node id 16 (no lane matches), row 0

using bf16 = __hip_bfloat16;
typedef __attribute__((ext_vector_type(8))) short short8;
typedef __attribute__((ext_vector_type(4))) short short4v;
typedef __attribute__((ext_vector_type(4))) float float4v;

__device__ __forceinline__ float bfbits2f(unsigned short u) {
    union { unsigned int i; float f; } v;
    v.i = ((unsigned int)u) << 16;
    return v.f;
}
__device__ __forceinline__ unsigned short f2bfbits(float f) {
    union { float f; unsigned int i; } v;
    v.f = f;
    unsigned int r = v.i + 0x7fffu + ((v.i >> 16) & 1u);  // RNE; finite inputs
    return (unsigned short)(r >> 16);
}

// Init: zero ALL group cursors; build W fragment-order planes so prep2's
// B-frag loads are lane-contiguous: Wf[((nt*2+ks)*64 + l)*8 + j] holds
// W[nt*16+(l&15)][ks*32+(l>>4)*8+j] split into bf16 hi/lo.
__global__ __launch_bounds__(256) void k_init(
    const float* __restrict__ W, int* __restrict__ gcur,
    unsigned short* __restrict__ Wfhi, unsigned short* __restrict__ Wflo)
{
    const int t = blockIdx.x * 256 + threadIdx.x;
    for (int i = t; i < NREP * GSTRIDE; i += 512) gcur[i] = 0;
    for (int o = t; o < HID * HID; o += 512) {
        const int j = o & 7, l = (o >> 3) & 63, ksnt = o >> 9;
        const int ks = ksnt & 1, nt = ksnt >> 1;
        const int c = l & 15, q = l >> 4;
        const float f = W[(size_t)(nt * 16 + c) * HID + ks * 32 + q * 8 + j];
        const unsigned short h = f2bfbits(f);
        Wfhi[o] = h;
        Wflo[o] = f2bfbits(f - bfbits2f(h));
    }
}

// Fused: blocks [0,LIN_BLOCKS) = MFMA linear (R1-proven: x staged via LDS so
// global reads are coalesced; W-frags from pre-swizzled planes). Blocks
// [LIN_BLOCKS,...) = two-phase LDS group binning (R1-proven: contiguous
// per-(block,group) writes -> no write amplification, amortized atomics).
__global__ __launch_bounds__(256, 4) void k_prep2(
    const float* __restrict__ x, const unsigned short* __restrict__ Wfhi,
    const unsigned short* __restrict__ Wflo, const float* __restrict__ b,
    bf16* __restrict__ m,
    const int* __restrict__ edges, int* __restrict__ gcur,
    int* __restrict__ binned)
{
    __shared__ union SM {
        struct { float xs[64 * 65]; } lin;                    // 16.6 KB, pad 65
        struct { int cnt[GSTRIDE]; int base[GSTRIDE]; } bin;  // 4 KB
    } sm;
    const int t = threadIdx.x;

    if (blockIdx.x < LIN_BLOCKS) {
        // Stage 64 node rows coalesced into LDS (padded stride 65).
        const int nb0 = blockIdx.x * 64;
        const float4* xg = reinterpret_cast<const float4*>(x) + (size_t)nb0 * 16;
        #pragma unroll
        for (int k = 0; k < 4; ++k) {
            const int f4 = t + k * 256;                 // float4 idx within block
            float4 v = make_float4(0.f, 0.f, 0.f, 0.f);
            if (nb0 * 16 + f4 < N_NODES * 16) v = xg[f4];
            const int r = f4 >> 4, fc = (f4 & 15) * 4;
            float* dst = &sm.lin.xs[r * 65 + fc];
            dst[0] = v.x; dst[1] = v.y; dst[2] = v.z; dst[3] = v.w;
        }
        __syncthreads();

        const int wv = t >> 6, l = t & 63;
        const int c = l & 15, q = l >> 4;
        const int tile = blockIdx.x * 4 + wv;
        if (tile >= N_NODES / 16) return;   // 6250 tiles cover 100k nodes exactly
        const int nb = tile * 16;

        // B-frags: lane-contiguous loads from pre-swizzled planes.
        const short8* wfh = reinterpret_cast<const short8*>(Wfhi);
        const short8* wfl = reinterpret_cast<const short8*>(Wflo);
        short8 Bhi[4][2], Blo[4][2];
        #pragma unroll
        for (int nt = 0; nt < 4; ++nt)
            #pragma unroll
            for (int ks = 0; ks < 2; ++ks) {
                const int fi = (nt * 2 + ks) * 64 + l;
                Bhi[nt][ks] = wfh[fi];
                Blo[nt][ks] = wfl[fi];
            }

        // A-frags from LDS (bank-conflict-free via pad), bf16 RNE convert.
        short8 Ahi[2];
        #pragma unroll
        for (int ks = 0; ks < 2; ++ks) {
            const float* xsrc = &sm.lin.xs[(wv * 16 + c) * 65 + ks * 32 + q * 8];
            #pragma unroll
            for (int j = 0; j < 8; ++j)
                Ahi[ks][j] = (short)f2bfbits(xsrc[j]);
        }

        float4v acc[4];
        #pragma unroll
        for (int nt = 0; nt < 4; ++nt) {
            const float bias = b[nt * 16 + c];
            acc[nt] = (float4v){bias, bias, bias, bias};
            #pragma unroll
            for (int ks = 0; ks < 2; ++ks) {
                acc[nt] = __builtin_amdgcn_mfma_f32_16x16x32_bf16(Ahi[ks], Bhi[nt][ks], acc[nt], 0, 0, 0);
                acc[nt] = __builtin_amdgcn_mfma_f32_16x16x32_bf16(Ahi[ks], Blo[nt][ks], acc[nt], 0, 0, 0);
            }
        }

        // C/D: col c = feature nt*16+c, row q*4+rg = node nb+q*4+rg
        unsigned short* mp = reinterpret_cast<unsigned short*>(m);
        #pragma unroll
        for (int nt = 0; nt < 4; ++nt)
            #pragma unroll
            for (int rg = 0; rg < 4; ++rg) {
                const float v = fmaxf(acc[nt][rg], 0.0f);
                mp[(size_t)(nb + q * 4 + rg) * HID + nt * 16 + c] = f2bfbits(v);
            }
    } else {
        int* cnt  = sm.bin.cnt;
        int* base = sm.bin.base;
        const int bb = blockIdx.x - LIN_BLOCKS;
        for (int i = t; i < GSTRIDE; i += 256) cnt[i] = 0;
        __syncthreads();

        const int e0 = bb * (256 * EPT);
        int gk[EPT], pk[EPT], sl[EPT];
        #pragma unroll
        for (int k = 0; k < EPT; ++k) {
            const int e = e0 + k * 256 + t;   // coalesced per k
            if (e < N_EDGES) {
                const int dst = edges[e];             // target
                const int src = edges[N_EDGES + e];   // source
                const int g = (int)((unsigned)dst / NG);   // magic-mul div
                gk[k] = g;
                pk[k] = ((dst - g * NG) << 17) | src;  // dl(8b) | src(17b)
                sl[k] = atomicAdd(&cnt[g], 1);
            } else gk[k] = -1;
        }
        __syncthreads();
        const int r = bb & (NREP - 1);
        for (int i = t; i < GROUPS; i += 256) {
            const int cc = cnt[i];
            base[i] = cc ? atomicAdd(&gcur[r * GSTRIDE + i], cc) : 0;
        }
        __syncthreads();
        #pragma unroll
        for (int k = 0; k < EPT; ++k) {
            if (gk[k] >= 0) {
                const int pos = base[gk[k]] + sl[k];
                if ((unsigned)pos < RCAP)   // unsigned: rejects corruption too
                    binned[(size_t)(r * GSTRIDE + gk[k]) * RCAP + pos] = pk[k];
            }
        }
    }
}

// hardware transpose read: per-lane addr = base + l*8; group q (l>>4) reads the
// 128B window at q*128: [4 slots][16 feats] bf16 row-major; lane gets feat l&15
// across the 4 slot-rows (learn_hip m156/m162 semantics).
#define TRREAD(dst, OFF) \
    asm volatile("ds_read_b64_tr_b16 %0, %1 offset:" #OFF \
                 : "=v"(dst) : "v"(traddr) : "memory")

// MFMA gather. Phase 1 is now an OCTANT-PHASED counting sort: each tile's
// list is ordered by rotated src-octant rk = ((src>>14) - (g&7)) & 7. Blocks
// dispatch round-robin across the 8 XCDs (bid%8), so all blocks co-resident
// on one XCD start at the SAME octant and sweep the same ~2MB m-range
// together -> that range stays L2-resident for the phase, cutting the
// scattered m re-fetch (the dominant gather traffic term). List order is
// semantically arbitrary (one-hot tags travel with slots), so the main loop
// is unchanged from the R3/R5-verified version: conflict-free staging writes
// (offset mod 128 = (l&7)*16), int2/int4 vector list reads, PADTAG tail
// padding, register prefetch rotation. Window row r holds slot 2r (pass A) /
// 2r+1 (pass B) -> k-order [0,2,4,6,1,3,5,7], compensated in one-hot build.
__global__ __launch_bounds__(GTHREADS, 6) void k_gather_mfma(
    const float* __restrict__ x, const bf16* __restrict__ m,
    const int* __restrict__ gcur, const int* __restrict__ binned,
    const float* __restrict__ nw, const float* __restrict__ nbias,
    float* __restrict__ out)
{
    __shared__ int tcnt[TILES];
    __shared__ int ocnt[TILES * NOCT];                  // 416 B
    __shared__ int obase[TILES * NOCT];                 // 416 B (place cursors)
    __shared__ int tlist[TILES * TCAP];                 // 19968 B
    __shared__ uint4 stg4[GWAVES * 128];                // 24576 B: 2KB per wave

    const int t = threadIdx.x;
    const int g = blockIdx.x;
    const int s_rot = g & 7;                            // XCD phase rotation
    for (int i = t; i < TILES * NOCT; i += GTHREADS) ocnt[i] = 0;
    __syncthreads();

    // Phase 1a: count per (tile, rotated-octant).
    // pr = dl(8b)<<17 | src(17b); tile = pr>>21; src = pr & 0x1FFFF.
    #pragma unroll
    for (int rr = 0; rr < NREP; ++rr) {
        int c = gcur[rr * GSTRIDE + g];
        if (c > RCAP) c = RCAP;
        const int* reg = binned + (size_t)(rr * GSTRIDE + g) * RCAP;
        for (int i = t; i < c; i += GTHREADS) {
            const int pr = reg[i];
            const int tile = pr >> 21;
            const int rk = (((pr & 0x1FFFF) >> 14) - s_rot) & 7;
            atomicAdd(&ocnt[tile * NOCT + rk], 1);
        }
    }
    __syncthreads();

    // Phase 1b: per-tile serial prefix over 8 octants; total -> tcnt.
    if (t < TILES) {
        int acc = 0;
        #pragma unroll
        for (int rk = 0; rk < NOCT; ++rk) {
            obase[t * NOCT + rk] = acc;
            acc += ocnt[t * NOCT + rk];
        }
        tcnt[t] = acc;
    }
    __syncthreads();

    // Phase 1c: place (binned re-read is L2-hot from 1a).
    #pragma unroll
    for (int rr = 0; rr < NREP; ++rr) {
        int c = gcur[rr * GSTRIDE + g];
        if (c > RCAP) c = RCAP;
        const int* reg = binned + (size_t)(rr * GSTRIDE + g) * RCAP;
        for (int i = t; i < c; i += GTHREADS) {
            const int pr = reg[i];
            const int tile = pr >> 21;
            const int rk = (((pr & 0x1FFFF) >> 14) - s_rot) & 7;
            const int slot = atomicAdd(&obase[tile * NOCT + rk], 1);
            if (slot < TCAP) tlist[tile * TCAP + slot] = pr & 0x1FFFFF;
        }
    }
    __syncthreads();

    const int wv = t >> 6, l = t & 63;
    const int q = l >> 4;            // MFMA k-group / tr-read window
    const int node16 = l & 15;       // node column this lane owns in D
    const int h  = l & 1;            // 16B half within a window row
    const int r2 = (l >> 1) & 3;     // window row this lane stages
    const int ft = (l >> 3) & 3;     // feat-16 group this lane stages
    const int qb = (l >> 5) & 1;     // window base (stores: qb and qb+2)
    const int fq = ft * 2 + h;       // 16B segment of the m-row to gather
    const int sA0 = qb * 8 + r2 * 2; // chunk-local slot (pass A); +1 pass B
    // conflict-free write offset: mod 128 = (r2*32 + h*16) = (l&7)*16
    const int wbyte = ft * 512 + qb * 128 + r2 * 32 + h * 16;
    char* stg_wave = (char*)(&stg4[0]) + (wv << 11);
    const unsigned traddr = (unsigned)(size_t)stg_wave + (unsigned)(l << 3);
    const uint4* mv = reinterpret_cast<const uint4*>(m);

    for (int tile = wv; tile < TILES; tile += GWAVES) {
        int K = tcnt[tile];
        if (K > TCAP) K = TCAP;
        const int lbase = tile * TCAP;
        const int nch = (K + 31) >> 5;

        // pad this tile's list tail so unguarded vector reads are harmless;
        // only the owning wave reads these slots.
        for (int i = K + l; i < nch * 32; i += 64) tlist[lbase + i] = PADTAG;
        asm volatile("s_waitcnt lgkmcnt(0)" ::: "memory");

        float4v acc0 = {0.f, 0.f, 0.f, 0.f};
        float4v acc1 = acc0, acc2 = acc0, acc3 = acc0;

        if (nch > 0) {
            // prologue: chunk 0 addresses + rows
            int2 pa = *reinterpret_cast<const int2*>(&tlist[lbase + sA0]);
            int2 pb = *reinterpret_cast<const int2*>(&tlist[lbase + sA0 + 16]);
            uint4 dA0 = mv[(size_t)(pa.x & 0x1FFFF) * 8 + fq];
            uint4 dB0 = mv[(size_t)(pa.y & 0x1FFFF) * 8 + fq];
            uint4 dA1 = mv[(size_t)(pb.x & 0x1FFFF) * 8 + fq];
            uint4 dB1 = mv[(size_t)(pb.y & 0x1FFFF) * 8 + fq];

            for (int ch = 0; ch < nch; ++ch) {
                const int k0 = ch << 5;
                // --- prefetch next chunk (wraps to 0 on last iter; harmless) ---
                const int kn = (ch + 1 < nch) ? (k0 + 32) : 0;
                const int2 npa = *reinterpret_cast<const int2*>(&tlist[lbase + kn + sA0]);
                const int2 npb = *reinterpret_cast<const int2*>(&tlist[lbase + kn + sA0 + 16]);
                const uint4 nA0 = mv[(size_t)(npa.x & 0x1FFFF) * 8 + fq];
                const uint4 nB0 = mv[(size_t)(npa.y & 0x1FFFF) * 8 + fq];
                const uint4 nA1 = mv[(size_t)(npb.x & 0x1FFFF) * 8 + fq];
                const uint4 nB1 = mv[(size_t)(npb.y & 0x1FFFF) * 8 + fq];

                // --- one-hot tags: 2 x int4, k-order compensated [0,2,4,6,1,3,5,7] ---
                const int tb = k0 + q * 8;
                const int4 t0 = *reinterpret_cast<const int4*>(&tlist[lbase + tb]);
                const int4 t1 = *reinterpret_cast<const int4*>(&tlist[lbase + tb + 4]);
                short8 bh;
                bh[0] = (short)(((t0.x >> 17) == node16) ? 0x3F80 : 0);
                bh[4] = (short)(((t0.y >> 17) == node16) ? 0x3F80 : 0);
                bh[1] = (short)(((t0.z >> 17) == node16) ? 0x3F80 : 0);
                bh[5] = (short)(((t0.w >> 17) == node16) ? 0x3F80 : 0);
                bh[2] = (short)(((t1.x >> 17) == node16) ? 0x3F80 : 0);
                bh[6] = (short)(((t1.y >> 17) == node16) ? 0x3F80 : 0);
                bh[3] = (short)(((t1.z >> 17) == node16) ? 0x3F80 : 0);
                bh[7] = (short)(((t1.w >> 17) == node16) ? 0x3F80 : 0);

                // --- pass A (slots 2r): stage windows qb, qb+2; transpose-read ---
                *reinterpret_cast<uint4*>(stg_wave + wbyte) = dA0;
                *reinterpret_cast<uint4*>(stg_wave + wbyte + 256) = dA1;
                short4v tA0, tA1, tA2, tA3;
                TRREAD(tA0, 0); TRREAD(tA1, 512); TRREAD(tA2, 1024); TRREAD(tA3, 1536);

                // --- pass B (slots 2r+1): same addresses (DS pipe is in-order) ---
                *reinterpret_cast<uint4*>(stg_wave + wbyte) = dB0;
                *reinterpret_cast<uint4*>(stg_wave + wbyte + 256) = dB1;
                short4v tB0, tB1, tB2, tB3;
                TRREAD(tB0, 0); TRREAD(tB1, 512); TRREAD(tB2, 1024); TRREAD(tB3, 1536);

                asm volatile("s_waitcnt lgkmcnt(0)" ::: "memory");
                __builtin_amdgcn_sched_barrier(0);
                const short8 a0 = __builtin_shufflevector(tA0, tB0, 0, 1, 2, 3, 4, 5, 6, 7);
                const short8 a1 = __builtin_shufflevector(tA1, tB1, 0, 1, 2, 3, 4, 5, 6, 7);
                const short8 a2 = __builtin_shufflevector(tA2, tB2, 0, 1, 2, 3, 4, 5, 6, 7);
                const short8 a3 = __builtin_shufflevector(tA3, tB3, 0, 1, 2, 3, 4, 5, 6, 7);
                acc0 = __builtin_amdgcn_mfma_f32_16x16x32_bf16(a0, bh, acc0, 0, 0, 0);
                acc1 = __builtin_amdgcn_mfma_f32_16x16x32_bf16(a1, bh, acc1, 0, 0, 0);
                acc2 = __builtin_amdgcn_mfma_f32_16x16x32_bf16(a2, bh, acc2, 0, 0, 0);
                acc3 = __builtin_amdgcn_mfma_f32_16x16x32_bf16(a3, bh, acc3, 0, 0, 0);

                // --- rotate prefetch into current ---
                pa = npa; pb = npb;
                dA0 = nA0; dB0 = nB0; dA1 = nA1; dB1 = nB1;
            }
        }

        // --- epilogue: residual + RMSNorm. Lane holds feats ft*16+q*4+{0..3}
        // of node g*NG + tile*16 + node16. ss partners (l^16,l^32) share node. ---
        const int dl = (tile << 4) + node16;
        const int n = g * NG + dl;
        if (dl < NG && n < N_NODES) {
            const float4* xr = reinterpret_cast<const float4*>(x) + (size_t)n * 16 + q;
            const float4 x0 = xr[0], x1 = xr[4], x2 = xr[8], x3 = xr[12];
            const float h00 = x0.x + acc0[0], h01 = x0.y + acc0[1], h02 = x0.z + acc0[2], h03 = x0.w + acc0[3];
            const float h10 = x1.x + acc1[0], h11 = x1.y + acc1[1], h12 = x1.z + acc1[2], h13 = x1.w + acc1[3];
            const float h20 = x2.x + acc2[0], h21 = x2.y + acc2[1], h22 = x2.z + acc2[2], h23 = x2.w + acc2[3];
            const float h30 = x3.x + acc3[0], h31 = x3.y + acc3[1], h32 = x3.z + acc3[2], h33 = x3.w + acc3[3];
            float ss = h00 * h00 + h01 * h01 + h02 * h02 + h03 * h03
                     + h10 * h10 + h11 * h11 + h12 * h12 + h13 * h13
                     + h20 * h20 + h21 * h21 + h22 * h22 + h23 * h23
                     + h30 * h30 + h31 * h31 + h32 * h32 + h33 * h33;
            ss += __shfl_xor(ss, 16, 64);
            ss += __shfl_xor(ss, 32, 64);
            const float inv = rsqrtf(ss * (1.0f / HID) + 1e-5f);
            const float4* nwp = reinterpret_cast<const float4*>(nw);
            const float4* nbp = reinterpret_cast<const float4*>(nbias);
            float4* op = reinterpret_cast<float4*>(out) + (size_t)n * 16 + q;
            {
                const float4 w = nwp[q], bb = nbp[q];
                float4 o;
                o.x = w.x * h00 * inv + bb.x; o.y = w.y * h01 * inv + bb.y;
                o.z = w.z * h02 * inv + bb.z; o.w = w.w * h03 * inv + bb.w;
                op[0] = o;
            }
            {
                const float4 w = nwp[4 + q], bb = nbp[4 + q];
                float4 o;
                o.x = w.x * h10 * inv + bb.x; o.y = w.y * h11 * inv + bb.y;
                o.z = w.z * h12 * inv + bb.z; o.w = w.w * h13 * inv + bb.w;
                op[4] = o;
            }
            {
                const float4 w = nwp[8 + q], bb = nbp[8 + q];
                float4 o;
                o.x = w.x * h20 * inv + bb.x; o.y = w.y * h21 * inv + bb.y;
                o.z = w.z * h22 * inv + bb.z; o.w = w.w * h23 * inv + bb.w;
                op[8] = o;
            }
            {
                const float4 w = nwp[12 + q], bb = nbp[12 + q];
                float4 o;
                o.x = w.x * h30 * inv + bb.x; o.y = w.y * h31 * inv + bb.y;
                o.z = w.z * h32 * inv + bb.z; o.w = w.w * h33 * inv + bb.w;
                op[12] = o;
            }
        }
    }
}

extern "C" void kernel_launch(void* const* d_in, const int* in_sizes, int n_in,
                              void* d_out, int out_size, void* d_ws, size_t ws_size,
                              hipStream_t stream) {
    const float* x     = (const float*)d_in[0];
    const int*   edges = (const int*)d_in[1];
    const float* W     = (const float*)d_in[2];
    const float* b     = (const float*)d_in[3];
    const float* nw    = (const float*)d_in[4];
    const float* nb    = (const float*)d_in[5];
    float* out = (float*)d_out;

    // Workspace: gcur 4KB | Wfhi 8KB @16K | Wflo 8KB @24K | binned 8.4MB @64K | m
    int* gcur = (int*)d_ws;
    unsigned short* Wfhi = (unsigned short*)((char*)d_ws + (1 << 14));
    unsigned short* Wflo = Wfhi + HID * HID;
    int*  binned = (int*)((char*)d_ws + (1 << 16));
    bf16* m      = (bf16*)((char*)d_ws + (1 << 16) +
                           (size_t)NREP * GSTRIDE * RCAP * sizeof(int));

    k_init<<<2, 256, 0, stream>>>(W, gcur, Wfhi, Wflo);
    k_prep2<<<LIN_BLOCKS + BIN_BLOCKS, 256, 0, stream>>>(x, Wfhi, Wflo, b, m, edges, gcur, binned);
    k_gather_mfma<<<GROUPS, GTHREADS, 0, stream>>>(x, m, gcur, binned, nw, nb, out);
}